// Round 15
// baseline (284.803 us; speedup 1.0000x reference)
//
#include <hip/hip_runtime.h>
#include <float.h>

#define N_TRAIN 50000
#define NBLKG   49           // 1024-col survivor groups
#define SLOT    64           // survivor slots per (row, group)
#define MPAD    1664         // 26*64 padded row count
#define DDIM    384
#define M_ROWS  1568         // 8*196
#define KNN     20
#define K2      24           // candidate-inclusion rank (margin over 20)
#define SELMAX  64
#define NCLS    21
#define CAPBUF  768
#define NENT2   (NBLKG * SLOT)   // 3136
#define SAMP    3072         // prepass sample columns

typedef __attribute__((ext_vector_type(8)))  short bf16x8;
typedef __attribute__((ext_vector_type(16))) float f32x16;

#define GLOAD_LDS16(gp, lp) \
  __builtin_amdgcn_global_load_lds((const __attribute__((address_space(1))) void*)(gp), \
                                   (__attribute__((address_space(3))) void*)(lp), 16, 0, 0)

// round-to-nearest-even f32 -> bf16
static __device__ __forceinline__ unsigned short f2bf(float f) {
  unsigned int u = __float_as_uint(f);
  unsigned int r = (u + 0x7fffu + ((u >> 16) & 1u)) >> 16;
  return (unsigned short)r;
}
static __device__ __forceinline__ float bf2f(unsigned short h) {
  return __uint_as_float(((unsigned int)h) << 16);
}
// order-preserving f32 -> u32 key
static __device__ __forceinline__ unsigned int flip32(unsigned int u) {
  return (u & 0x80000000u) ? ~u : (u | 0x80000000u);
}

// ---------------- transpose labels [256][50000] i32 -> [50000][256] u8 --------
__global__ __launch_bounds__(256) void transpose_labels(const int* __restrict__ labels,
                                                        unsigned char* __restrict__ labT) {
  __shared__ int tile[64][65];
  const int t  = threadIdx.x;
  const int c0 = blockIdx.x * 64;
  const int r0 = blockIdx.y * 64;
#pragma unroll
  for (int i = 0; i < 16; ++i) {
    int idx = i * 256 + t;
    int r = idx >> 6, c = idx & 63;
    int cc = c0 + c;
    tile[r][c] = (cc < N_TRAIN) ? labels[(size_t)(r0 + r) * N_TRAIN + cc] : 0;
  }
  __syncthreads();
#pragma unroll
  for (int i = 0; i < 16; ++i) {
    int idx = i * 256 + t;
    int c = idx >> 6, r = idx & 63;
    int cc = c0 + c;
    if (cc < N_TRAIN) labT[(size_t)cc * 256 + r0 + r] = (unsigned char)tile[r][c];
  }
}

// ------- pack test -> Apack 32x32-frag-major: [mt=52][ks=24][lane=64][8] bf16 --
__global__ __launch_bounds__(256) void conv_Apack(const float* __restrict__ test,
                                                  unsigned short* __restrict__ Apack) {
  int o = blockIdx.x * 256 + threadIdx.x;        // over 52*24*512 = 638,976
  if (o >= (MPAD / 32) * 24 * 512) return;
  int j = o & 7;
  int l = (o >> 3) & 63;
  int rest = o >> 9;
  int ks = rest % 24, mt = rest / 24;
  int row = mt * 32 + (l & 31);
  int k = ks * 16 + (l >> 5) * 8 + j;
  Apack[o] = (row < M_ROWS) ? f2bf(test[(size_t)row * DDIM + k]) : (unsigned short)0;
}

// -- fused: train [384][50000] f32 -> Bpack 32x32-frag-major bf16 + trainT f32 --
__global__ __launch_bounds__(256) void trans_train_fused(const float* __restrict__ train,
                                                         unsigned short* __restrict__ Bpack,
                                                         float* __restrict__ trainT) {
  __shared__ float tile[64][65];   // [k-in-tile][col-in-tile]
  const int t  = threadIdx.x;
  const int c0 = blockIdx.x * 64;   // col base (0..50176)
  const int r0 = blockIdx.y * 64;   // k base (0..384)
#pragma unroll
  for (int i = 0; i < 16; ++i) {
    int idx = i * 256 + t;
    int r = idx >> 6, c = idx & 63;
    int cc = c0 + c;
    tile[r][c] = (cc < N_TRAIN) ? train[(size_t)(r0 + r) * N_TRAIN + cc] : 0.f;
  }
  __syncthreads();
#pragma unroll
  for (int it = 0; it < 2; ++it) {
    int u = it * 256 + t;
    int c = u & 63, koctL = u >> 6;            // koctL 0..7
    int col = c0 + c;
    int koct = (r0 >> 3) + koctL;              // global k-oct 0..47
    int ks = koct >> 1, half = koct & 1;
    int nt = col >> 5, l = (c & 31) + half * 32;
    size_t base = ((size_t)(nt * 24 + ks) * 64 + l) * 8;
    ushort4 h0, h1;
    h0.x = f2bf(tile[koctL * 8 + 0][c]); h0.y = f2bf(tile[koctL * 8 + 1][c]);
    h0.z = f2bf(tile[koctL * 8 + 2][c]); h0.w = f2bf(tile[koctL * 8 + 3][c]);
    h1.x = f2bf(tile[koctL * 8 + 4][c]); h1.y = f2bf(tile[koctL * 8 + 5][c]);
    h1.z = f2bf(tile[koctL * 8 + 6][c]); h1.w = f2bf(tile[koctL * 8 + 7][c]);
    *(ushort4*)&Bpack[base]     = h0;
    *(ushort4*)&Bpack[base + 4] = h1;
  }
#pragma unroll
  for (int i = 0; i < 16; ++i) {
    int idx = i * 256 + t;
    int c = idx >> 6, r = idx & 63;
    int cc = c0 + c;
    if (cc < N_TRAIN) trainT[(size_t)cc * DDIM + r0 + r] = tile[r][c];
  }
}

// ---------------- prepass GEMM: sample cols 0..3071 -> skey u16 ---------------
// grid 156 = 26 mblk x 6 (512-col). Same K-loop as main; writes raw k16 keys.
__global__ __launch_bounds__(512, 4) void prepass_gemm(const unsigned short* __restrict__ Apack,
                                                       const unsigned short* __restrict__ Bpack,
                                                       unsigned short* __restrict__ skey) {
  __shared__ unsigned short Al[24576];
  const int t = threadIdx.x;
  const int mblk = blockIdx.x % 26, scol = blockIdx.x / 26;
  const int m0 = mblk * 64, colbase = scol * 512;
  const int wid = t >> 6, lane = t & 63;
  const int wr = wid >> 2, wc = wid & 3;
  const int l31 = lane & 31, lh = lane >> 5;

  const unsigned short* Asrc = Apack + (size_t)(mblk * 2) * 24 * 512;
#pragma unroll
  for (int j = 0; j < 6; ++j)
    GLOAD_LDS16(Asrc + (size_t)j * 4096 + wid * 512 + lane * 8,
                &Al[j * 4096 + wid * 512]);
  __syncthreads();

  const unsigned short* Bb = Bpack + (size_t)((colbase >> 5) + wc * 4) * 24 * 512;
  f32x16 acc[4];
#pragma unroll
  for (int n = 0; n < 4; ++n)
#pragma unroll
    for (int q = 0; q < 16; ++q) acc[n][q] = 0.f;

#pragma unroll 4
  for (int ks = 0; ks < 24; ++ks) {
    bf16x8 a = *(const bf16x8*)&Al[((wr * 24 + ks) * 64 + lane) * 8];
    bf16x8 b[4];
#pragma unroll
    for (int n = 0; n < 4; ++n)
      b[n] = *(const bf16x8*)&Bb[((size_t)(n * 24 + ks) * 64 + lane) * 8];
#pragma unroll
    for (int n = 0; n < 4; ++n)
      acc[n] = __builtin_amdgcn_mfma_f32_32x32x16_bf16(a, b[n], acc[n], 0, 0, 0);
  }

#pragma unroll
  for (int reg = 0; reg < 16; ++reg) {
    const int rowl = (reg & 3) + 8 * (reg >> 2) + 4 * lh;
    const int row = m0 + wr * 32 + rowl;
#pragma unroll
    for (int n = 0; n < 4; ++n) {
      const int col = colbase + wc * 128 + n * 32 + l31;
      unsigned int k16 = flip32(__float_as_uint(acc[n][reg])) >> 16;
      skey[(size_t)row * SAMP + col] = (unsigned short)k16;
    }
  }
}

// ---------------- tau: per-row exact 24th-largest sample key ------------------
__global__ __launch_bounds__(256) void tau_kernel(const unsigned short* __restrict__ skey,
                                                  unsigned short* __restrict__ tau16) {
  const int m = blockIdx.x, t = threadIdx.x;
  if (m >= M_ROWS) { if (t == 0) tau16[m] = 0xFFFFu; return; }
  __shared__ unsigned int smax[256];
  __shared__ unsigned int sbuf[CAPBUF];
  __shared__ unsigned int scnt, sTauA, sE24;
  if (t == 0) { scnt = 0u; sTauA = 0u; sE24 = 0u; }
  __syncthreads();

  unsigned int mx = 0u;
  for (int i = t; i < SAMP; i += 256) {
    unsigned int k = skey[(size_t)m * SAMP + i];
    unsigned int e = (k << 16) | (0xFFFFu - (unsigned int)i);   // unique
    mx = max(mx, e);
  }
  smax[t] = mx;
  __syncthreads();
  {
    int rnk = 0;
    for (int j = 0; j < 256; ++j) rnk += (smax[j] > mx) ? 1 : 0;
    if (rnk == K2 - 1) sTauA = mx;
  }
  __syncthreads();
  const unsigned int tauA = sTauA;
  for (int i = t; i < SAMP; i += 256) {
    unsigned int k = skey[(size_t)m * SAMP + i];
    unsigned int e = (k << 16) | (0xFFFFu - (unsigned int)i);
    if (e >= tauA) { unsigned int p = atomicAdd(&scnt, 1u); if (p < CAPBUF) sbuf[p] = e; }
  }
  __syncthreads();
  const int C = (int)min(scnt, (unsigned int)CAPBUF);
  for (int s = t; s < C; s += 256) {
    unsigned int e = sbuf[s];
    int rk = 0;
    for (int j = 0; j < C; ++j) rk += (sbuf[j] > e) ? 1 : 0;
    if (rk == K2 - 1) sE24 = e;
  }
  __syncthreads();
  if (t == 0) tau16[m] = (unsigned short)(sE24 >> 16);
}

// ---------------- main MFMA GEMM with threshold epilogue ----------------------
// K-loop identical to r14 (A-in-LDS 48KB once, B reg-streamed). Epilogue: ONE
// f32 compare/element vs per-row T = unflip(tau16); rare survivors appended to
// surv[row][ngrp][64] via LDS-atomic counters. Overflow -> ovf flag.
__global__ __launch_bounds__(512, 4) void mfma_gemm(const unsigned short* __restrict__ Apack,
                                                    const unsigned short* __restrict__ Bpack,
                                                    const unsigned short* __restrict__ tau16,
                                                    unsigned int* __restrict__ surv,
                                                    unsigned char* __restrict__ ovf) {
  __shared__ unsigned short Al[24576];   // 48 KB
  __shared__ float Tf[64];
  __shared__ int cnt[64];
  const int t = threadIdx.x;

  // bijective XCD chunking: nwg = 1274 = 8*159 + 2
  const int flat = blockIdx.x;
  const int xcd = flat & 7, jj = flat >> 3;
  const int wg = (xcd < 2 ? xcd * 160 : 320 + (xcd - 2) * 159) + jj;
  const int mblk = wg % 26, ngrp = wg / 26;   // 26 consecutive wg share ngrp
  const int m0 = mblk * 64;

  const int wid = t >> 6, lane = t & 63;
  const int wr = wid >> 2, wc = wid & 3;      // 2 x 4 waves; wave 32 rows x 128 cols
  const int l31 = lane & 31, lh = lane >> 5;

  if (t < 64) {
    cnt[t] = 0;
    unsigned int k = ((unsigned int)tau16[m0 + t]) << 16;
    unsigned int b = (k & 0x80000000u) ? (k & 0x7fffffffu) : ~k;   // unflip
    Tf[t] = __uint_as_float(b);
  }
  const unsigned short* Asrc = Apack + (size_t)(mblk * 2) * 24 * 512;
#pragma unroll
  for (int j = 0; j < 6; ++j)
    GLOAD_LDS16(Asrc + (size_t)j * 4096 + wid * 512 + lane * 8,
                &Al[j * 4096 + wid * 512]);
  __syncthreads();

#pragma unroll 1
  for (int s = 0; s < 2; ++s) {
    const int colbase = ngrp * 1024 + s * 512;
    const unsigned short* Bb = Bpack + (size_t)((colbase >> 5) + wc * 4) * 24 * 512;

    f32x16 acc[4];
#pragma unroll
    for (int n = 0; n < 4; ++n)
#pragma unroll
      for (int q = 0; q < 16; ++q) acc[n][q] = 0.f;

#pragma unroll 4
    for (int ks = 0; ks < 24; ++ks) {
      bf16x8 a = *(const bf16x8*)&Al[((wr * 24 + ks) * 64 + lane) * 8];
      bf16x8 b[4];
#pragma unroll
      for (int n = 0; n < 4; ++n)
        b[n] = *(const bf16x8*)&Bb[((size_t)(n * 24 + ks) * 64 + lane) * 8];
#pragma unroll
      for (int n = 0; n < 4; ++n)
        acc[n] = __builtin_amdgcn_mfma_f32_32x32x16_bf16(a, b[n], acc[n], 0, 0, 0);
    }

    // ---- threshold epilogue: 1 cmp/element; rare append ----
#pragma unroll
    for (int reg = 0; reg < 16; ++reg) {
      const int rowl = (reg & 3) + 8 * (reg >> 2) + 4 * lh;
      const float T = Tf[wr * 32 + rowl];
      int hit = 0;
#pragma unroll
      for (int n = 0; n < 4; ++n) hit |= (acc[n][reg] >= T) ? (1 << n) : 0;
      if (__any(hit)) {
        const int row = m0 + wr * 32 + rowl;
#pragma unroll
        for (int n = 0; n < 4; ++n) {
          if (hit & (1 << n)) {
            const int col = colbase + wc * 128 + n * 32 + l31;
            if (col < N_TRAIN) {
              unsigned int k16 = flip32(__float_as_uint(acc[n][reg])) >> 16;
              unsigned int e = (k16 << 16) | (0xFFFFu - (unsigned int)col);
              int slot = atomicAdd(&cnt[wr * 32 + rowl], 1);
              if (slot < SLOT) surv[((size_t)row * NBLKG + ngrp) * SLOT + slot] = e;
            }
          }
        }
      }
    }
  }
  __syncthreads();
  if (t < 64 && cnt[t] > SLOT) ovf[(size_t)(m0 + t) * NBLKG + ngrp] = 1;
}

// --------- fused tail: survivors -> exact top-24 -> f64 refine -> vote --------
__global__ __launch_bounds__(256) void tail_fused(const unsigned int* __restrict__ surv,
                                                  const unsigned char* __restrict__ ovf,
                                                  const float* __restrict__ test,
                                                  const float* __restrict__ trainT,
                                                  const unsigned char* __restrict__ labT,
                                                  int* __restrict__ out) {
  const int t = threadIdx.x, m = blockIdx.x;
  __shared__ unsigned int ent[NENT2];   // 12.5 KB
  __shared__ unsigned int smax[256];
  __shared__ unsigned int sbuf[CAPBUF];
  __shared__ unsigned int scnt, sTauA, sE24, ccnt2;
  __shared__ short flist[64];
  __shared__ int fcnt, sC2;
  __shared__ unsigned int cbuf[192];
  __shared__ int    selC[SELMAX];
  __shared__ double rvs[SELMAX];
  __shared__ double sv2[SELMAX];
  __shared__ int    si2[SELMAX];
  __shared__ double earr[KNN];
  __shared__ double wv[KNN];
  __shared__ int    wi[KNN];

  if (t == 0) { scnt = 0u; fcnt = 0; ccnt2 = 0u; sC2 = 0; sTauA = 0u; sE24 = 0u; }
  for (int i = t; i < NENT2; i += 256) ent[i] = surv[(size_t)m * NENT2 + i];
  for (int i = t; i < NBLKG; i += 256)
    if (ovf[(size_t)m * NBLKG + i]) { int p = atomicAdd(&fcnt, 1); if (p < 64) flist[p] = (short)i; }
  __syncthreads();

  // tauA = 24th largest of per-thread maxima (ties by tid; zeros possible)
  unsigned int mx = 0u;
  for (int i = t; i < NENT2; i += 256) mx = max(mx, ent[i]);
  smax[t] = mx;
  __syncthreads();
  {
    int rnk = 0;
    for (int j = 0; j < 256; ++j)
      rnk += (smax[j] > mx || (smax[j] == mx && j < t)) ? 1 : 0;
    if (rnk == K2 - 1) sTauA = mx;
  }
  __syncthreads();
  const unsigned int tauA = sTauA;

  for (int i = t; i < NENT2; i += 256) {
    unsigned int e = ent[i];
    if (e != 0u && e >= tauA) { unsigned int p = atomicAdd(&scnt, 1u); if (p < CAPBUF) sbuf[p] = e; }
  }
  __syncthreads();
  const int C = (int)min(scnt, (unsigned int)CAPBUF);
  for (int s = t; s < C; s += 256) {
    unsigned int e = sbuf[s];
    int rk = 0;
    for (int j = 0; j < C; ++j) rk += (sbuf[j] > e) ? 1 : 0;
    if (rk == K2 - 1) sE24 = e;
  }
  __syncthreads();
  const unsigned int k24 = sE24 >> 16;

  // candidates: survivors with key >= k24 (complete: surv ⊇ {k16 >= k24})
  for (int i = t; i < NENT2; i += 256) {
    unsigned int e = ent[i];
    if (e != 0u && (e >> 16) >= k24) {
      unsigned int p = atomicAdd(&ccnt2, 1u);
      if (p < 192) cbuf[p] = e;
    }
  }
  __syncthreads();

  // rescan overflowed 1024-col groups (statistically never)
  const int FC = min(fcnt, 64);
  for (int q = 0; q < FC; ++q) {
    const int fb = flist[q];
#pragma unroll 1
    for (int cc = 0; cc < 4; ++cc) {
      const int col = fb * 1024 + cc * 256 + t;
      if (col < N_TRAIN) {
        const float* Tc = trainT + (size_t)col * DDIM;
        const float* Tr = test + (size_t)m * DDIM;
        float s0 = 0.f;
        for (int k = 0; k < DDIM; ++k)
          s0 = fmaf(bf2f(f2bf(Tr[k])), bf2f(f2bf(Tc[k])), s0);
        unsigned int key = flip32(__float_as_uint(s0)) >> 16;
        if (key + 1u >= k24) {
          unsigned int e = (key << 16) | (0xFFFFu - (unsigned int)col);
          unsigned int p = atomicAdd(&ccnt2, 1u);
          if (p < 192) cbuf[p] = e;
        }
      }
    }
  }
  __syncthreads();
  const int CC = (int)min(ccnt2, 192u);

  // rank-select candidates by u32 desc -> selC[0..C2)
  for (int s = t; s < CC; s += 256) {
    unsigned int e = cbuf[s];
    int rk = 0;
    for (int j = 0; j < CC; ++j) rk += (cbuf[j] > e) ? 1 : 0;
    if (rk < SELMAX) {
      selC[rk] = 0xFFFF - (int)(e & 0xFFFFu);
      atomicMax(&sC2, rk + 1);
    }
  }
  __syncthreads();
  const int C2 = sC2 < SELMAX ? sC2 : SELMAX;

  // ---- f64 refine of C2 cands (4 waves split cands, lanes over d) ----
  const int wid = t >> 6, lane = t & 63;
  float tr[DDIM / 64];
#pragma unroll
  for (int dd = 0; dd < DDIM / 64; ++dd)
    tr[dd] = test[(size_t)m * DDIM + dd * 64 + lane];
#pragma unroll 1
  for (int c = wid; c < C2; c += 4) {
    const float* Tc = trainT + (size_t)selC[c] * DDIM;
    double s = 0.0;
#pragma unroll
    for (int dd = 0; dd < DDIM / 64; ++dd)
      s += (double)tr[dd] * (double)Tc[dd * 64 + lane];
#pragma unroll
    for (int off = 32; off > 0; off >>= 1) s += __shfl_xor(s, off);
    if (lane == 0) rvs[c] = s;
  }
  __syncthreads();

  if (t < C2) {
    double v = rvs[t]; int id = selC[t];
    int r = 0;
    for (int n = 0; n < C2; ++n)
      r += (rvs[n] > v || (rvs[n] == v && selC[n] < id)) ? 1 : 0;
    sv2[r] = v; si2[r] = id;
  }
  __syncthreads();

  if (t < KNN) earr[t] = exp(sv2[t] - sv2[0]);
  __syncthreads();
  if (t < KNN) {
    double ssum = 0.0;
    for (int k = 0; k < KNN; ++k) ssum += earr[k];
    wv[t] = earr[t] / ssum;
    wi[t] = si2[t];
  }
  __syncthreads();

  // ---- per-pixel weighted vote (f64) + argmax ----
  unsigned int packed[5];
#pragma unroll
  for (int q = 0; q < 5; ++q) {
    unsigned int p = 0;
#pragma unroll
    for (int j = 0; j < 4; ++j)
      p |= (unsigned int)labT[(size_t)wi[q * 4 + j] * 256 + t] << (8 * j);
    packed[q] = p;
  }
  double best = -1.0; int bc = 0;
#pragma unroll 1
  for (int c = 0; c < NCLS; ++c) {
    double s = 0.0;
#pragma unroll
    for (int k = 0; k < KNN; ++k) {
      unsigned int lab = (packed[k >> 2] >> ((k & 3) * 8)) & 255u;
      s += (lab == (unsigned int)c) ? wv[k] : 0.0;
    }
    if (s > best) { best = s; bc = c; }
  }
  const int b = m / 196, p = m % 196;
  const int py = p / 14, px = p % 14;
  const int i = t >> 4, j = t & 15;
  out[((size_t)b * 224 + py * 16 + i) * 224 + px * 16 + j] = bc;
}

// ---------------- launch ------------------------------------------------------
// ws layout (bytes), total ~160.6 MB (< ~307 MB poisoned ws):
//   labT   @ 0           : 12,800,000
//   Apack  @ 12,800,000  :  1,277,952  (u16 [52][24][64][8])
//   Bpack  @ 14,077,952  : 38,535,168  (u16 [1568][24][64][8])
//   trainT @ 52,613,120  : 76,800,000  (f32 [50000][384])
//   skey   @ 129,413,120 : 10,223,616  (u16 [1664][3072])
//   tau16  @ 139,636,736 :      3,328
//   surv   @ 139,640,320 : 20,873,216  (u32 [1664][49][64], memset 0)
//   ovf    @ 160,513,536 :     81,536  (u8  [1664][49],     memset 0)
extern "C" void kernel_launch(void* const* d_in, const int* in_sizes, int n_in,
                              void* d_out, int out_size, void* d_ws, size_t ws_size,
                              hipStream_t stream) {
  const float* test  = (const float*)d_in[0];   // [1568][384]
  const float* train = (const float*)d_in[1];   // [384][50000]
  const int* labels  = (const int*)d_in[2];     // [256][50000]
  int* out = (int*)d_out;
  char* ws = (char*)d_ws;

  unsigned char*  labT   = (unsigned char*)ws;
  unsigned short* Apack  = (unsigned short*)(ws + 12800000);
  unsigned short* Bpack  = (unsigned short*)(ws + 14077952);
  float*          trainT = (float*)(ws + 52613120);
  unsigned short* skey   = (unsigned short*)(ws + 129413120);
  unsigned short* tau16  = (unsigned short*)(ws + 139636736);
  unsigned int*   surv   = (unsigned int*)(ws + 139640320);
  unsigned char*  ovf    = (unsigned char*)(ws + 160513536);

  hipMemsetAsync(surv, 0, 20873216 + 81536, stream);   // surv + ovf (contiguous)
  transpose_labels<<<dim3(782, 4), 256, 0, stream>>>(labels, labT);
  conv_Apack<<<dim3((MPAD / 32) * 24 * 512 / 256), 256, 0, stream>>>(test, Apack);
  trans_train_fused<<<dim3(784, 6), 256, 0, stream>>>(train, Bpack, trainT);
  prepass_gemm<<<dim3(156), 512, 0, stream>>>(Apack, Bpack, skey);
  tau_kernel<<<dim3(MPAD), 256, 0, stream>>>(skey, tau16);
  mfma_gemm<<<dim3(1274), 512, 0, stream>>>(Apack, Bpack, tau16, surv, ovf);
  tail_fused<<<dim3(M_ROWS), 256, 0, stream>>>(surv, ovf, test, trainT, labT, out);
}